// Round 10
// baseline (641.170 us; speedup 1.0000x reference)
//
#include <hip/hip_runtime.h>
#include <hip/hip_bf16.h>
#include <cstdint>

// Problem constants: B=8, L=4096, D=768, Y=2048
#define BB 8
#define LL 4096
#define DD 768
#define YY 2048
#define NBLK ((LL / 128) * (YY / 128) * BB)   // 4096 fused blocks

typedef unsigned short u16;
typedef __bf16 bf16x8 __attribute__((ext_vector_type(8)));
typedef __bf16 bf16x2 __attribute__((ext_vector_type(2)));
typedef float f32x16 __attribute__((ext_vector_type(16)));

__device__ __forceinline__ u16 f2bf(float f) {
    uint32_t u = __float_as_uint(f);
    u += 0x7fffu + ((u >> 16) & 1u);   // RNE
    return (u16)(u >> 16);
}

__device__ __forceinline__ uint32_t pkbf(float a, float b) {
#if __has_builtin(__builtin_amdgcn_cvt_pk_bf16_f32)
    bf16x2 p = __builtin_amdgcn_cvt_pk_bf16_f32(a, b);
    return __builtin_bit_cast(uint32_t, p);
#else
    return (uint32_t)f2bf(a) | ((uint32_t)f2bf(b) << 16);
#endif
}

#define GLL(src, dst) \
    __builtin_amdgcn_global_load_lds((const __attribute__((address_space(1))) unsigned int*)(src), \
                                     (__attribute__((address_space(3))) unsigned int*)(dst), 16, 0, 0)

// ---- prologue: cast x/U/fw to bf16 in TILED layout + zero rowsum/ynum/counter ----
// Tiled bf16 layout: 32-row panels, chunk-major within panel:
//   addr(row, d) = (row>>5)*24576 + (d>>3)*256 + (row&31)*8 + (d&7)   [u16]
// (a) fused GLL staging reads contiguous 1KB/wave, (b) 32x32x16 fragment ds_reads are
// fully lane-linear (the empirically 0-conflict class, R16-verified).
__global__ __launch_bounds__(256) void prep_k(const float* __restrict__ x,
                                              const float* __restrict__ Uw,
                                              const float* __restrict__ fw,
                                              u16* __restrict__ x16, u16* __restrict__ U16,
                                              u16* __restrict__ fw16,
                                              float* __restrict__ rz,   // rowsum+ynum (contig)
                                              float* __restrict__ out0) {
    __shared__ u16 lds[32 * 34];                 // 32 rows x 32 u16, stride 34 (17 dw, odd)
    const int id = blockIdx.x, t = threadIdx.x;
    const float* src; u16* dst; int tile;
    if (id < 24576)      { tile = id;          src = x;  dst = x16;  }   // 1024 panels x 24
    else if (id < 26112) { tile = id - 24576;  src = Uw; dst = U16;  }   // 64 panels x 24
    else                 { tile = id - 26112;  src = fw; dst = fw16; }
    const int rt = tile / 24, dt = tile % 24;    // row-panel, d-tile (32 d each)
    const float* in = src + (size_t)rt * 32 * DD + dt * 32;
    // phase 1: read 32x32 floats (coalesced float4), cvt, store to padded LDS
    {
        const int r = t >> 3, dq = (t & 7) * 4;
        float4 v = *(const float4*)(in + (size_t)r * DD + dq);
        u16* p = &lds[r * 34 + dq];
        *(uint32_t*)(p)     = pkbf(v.x, v.y);
        *(uint32_t*)(p + 2) = pkbf(v.z, v.w);
    }
    __syncthreads();
    // phase 2: write chunk-major: out u16 idx t*4 == c*256 + r*8 + half*4
    {
        const int c = t >> 6, r = (t >> 1) & 31, half = t & 1;
        const u16* p = &lds[r * 34 + c * 8 + half * 4];
        uint2 o;
        o.x = *(const uint32_t*)(p);
        o.y = *(const uint32_t*)(p + 2);
        *(uint2*)(dst + (size_t)rt * 24576 + dt * 1024 + t * 4) = o;
    }
    if (id < 32) {                               // zero rowsum+ynum (32768 floats)
        ((float4*)rz)[id * 256 + t] = make_float4(0.f, 0.f, 0.f, 0.f);
        if (id == 0 && t == 0) out0[0] = 0.f;    // zero bits = int 0 (block counter)
    }
}

// ---------------- FUSED kernel: S=U.x^T and G=fw.x^T, epilogue sum exp(S), exp(S)*G ------
// y[b,r] = sum_l exp(att[r,l]) * G[r,l] / rowsum[r]   (summation order swapped).
// R16 (207 us, MfmaUtil 46, 0 conflicts): tiled layout + 32x32x16 + LDS for all operands.
// R19 (U/W direct from L2 via volatile asm loads): 215 us -- marginally WORSE; the LDS
//   weight path was not binding. Reverted to R16 compute.
// R20 changes:
//  (1) ONE barrier per K-tile (was 2): per tile { WAITL; WAITV(6); BAR; STAGE(i+2);
//      COMPUTE(i) }. Safety: all waves' reads of buf(i-1) are WAITL'd before BAR, and
//      the overwriting STAGE is after BAR; all waves' GLLs for tile i are WAITV'd
//      before BAR, COMPUTE after. Ledger: 6 GLL/stage, 12 outstanding steady.
//  (2) CE-loss folded in via last-block atomic-counter pattern (counter = out[0];
//      __threadfence + device-scope atomics; agent-scope loads for rowsum/ynum to
//      dodge per-XCD L2 staleness). Saves one dispatch + inter-kernel gap.
__global__ __launch_bounds__(256, 2) void fused_k(const u16* __restrict__ Xg, const u16* __restrict__ Ug,
                                                  const u16* __restrict__ Wg,
                                                  float* __restrict__ rowsum0, float* __restrict__ ynum0,
                                                  const float* __restrict__ fb,
                                                  const int* __restrict__ tgt,
                                                  float* __restrict__ out0,
                                                  float* __restrict__ yv) {
    __shared__ u16 As[3 * 4096];      // x tile: 128 l x 32 k, chunk-major (3-buf, 24 KB)
    __shared__ u16 Us[3 * 4096];      // U tile (24 KB)
    __shared__ u16 Ws[3 * 4096];      // fw tile (24 KB)
    __shared__ int lastB;
    __shared__ float smx[4], ssum[4], stv2[4];
    const int id = blockIdx.x;
    const int b = id & 7;             // batch pinned per XCD (%8 round-robin heuristic)
    const int r = id >> 3;            // 0..511
    const int yhalf = r >> 8;         // 0..1   (outer: U/fw half swapped once)
    const int q = r & 255;
    const int mblk = q >> 3;          // 0..31  (middle: x-tile advances, U/fw-half L2-hot)
    const int nblk = (yhalf << 3) + (q & 7);    // inner 8 y-blocks share one x-tile
    const u16* A = Xg + (size_t)b * LL * DD;    // b offset = b*128 panels
    float* rowsum = rowsum0 + (size_t)b * YY;
    float* ynum   = ynum0 + (size_t)b * YY;
    const int m0 = mblk * 128;        // l
    const int n0 = nblk * 128;        // y
    const int t = threadIdx.x;
    const int lane = t & 63;
    const int w = t >> 6;             // wave 0..3
    const int wm = (w >> 1) * 64;     // l-offset of wave
    const int wn = (w & 1) * 64;      // y-offset of wave
    const int l31 = lane & 31;
    const int lh  = lane >> 5;

    // ---- staging (R16): dest slot s=t (c0) / s=t+256 (c1) holds (rb=s>>7, c=(s>>5)&3,
    // r=s&31); per-wave 1KB contiguous global read.
    const int sc = ((t >> 5) & 3) * 256 + (t & 31) * 8;
    const u16* Ab0 = A + (size_t)((m0 >> 5) + (t >> 7)) * 24576 + sc;       // l rows 0..63
    const u16* Ab1 = Ab0 + 2 * 24576;                                        // l rows 64..127
    const u16* Ub0 = Ug + (size_t)((n0 >> 5) + (t >> 7)) * 24576 + sc;      // y rows 0..63
    const u16* Ub1 = Ub0 + 2 * 24576;                                        // y rows 64..127
    const u16* Wb0 = Wg + (size_t)((n0 >> 5) + (t >> 7)) * 24576 + sc;
    const u16* Wb1 = Wb0 + 2 * 24576;
    const int c0 = t * 8, c1 = (t + 256) * 8;

    f32x16 aS[2][2] = {};
    f32x16 aG[2][2] = {};

    // ---- fragment reads: fully lane-linear (0-conflict, R16-verified)
    const int a0 = (wm >> 5) * 1024 + lane * 8;
    const int b0 = (wn >> 5) * 1024 + lane * 8;

#define STAGE(bi)                                                       \
    {                                                                   \
        GLL(Ab0, As + (bi) * 4096 + c0);                                \
        GLL(Ab1, As + (bi) * 4096 + c1);                                \
        GLL(Ub0, Us + (bi) * 4096 + c0);                                \
        GLL(Ub1, Us + (bi) * 4096 + c1);                                \
        GLL(Wb0, Ws + (bi) * 4096 + c0);                                \
        GLL(Wb1, Ws + (bi) * 4096 + c1);                                \
        Ab0 += 1024; Ab1 += 1024; Ub0 += 1024; Ub1 += 1024;             \
        Wb0 += 1024; Wb1 += 1024;                                       \
    }

#define M32(a, bb, c) __builtin_amdgcn_mfma_f32_32x32x16_bf16(a, bb, c, 0, 0, 0)

#define COMPUTE(p)                                                                  \
    {                                                                               \
        bf16x8 af[2][2], bu[2][2], bw[2][2];                                        \
        _Pragma("unroll") for (int ms = 0; ms < 2; ++ms) {                          \
            af[ms][0] = *(const bf16x8*)(As + (p) + a0 + ms * 1024);                \
            af[ms][1] = *(const bf16x8*)(As + (p) + a0 + ms * 1024 + 512);          \
        }                                                                           \
        _Pragma("unroll") for (int ns = 0; ns < 2; ++ns) {                          \
            bu[ns][0] = *(const bf16x8*)(Us + (p) + b0 + ns * 1024);                \
            bu[ns][1] = *(const bf16x8*)(Us + (p) + b0 + ns * 1024 + 512);          \
            bw[ns][0] = *(const bf16x8*)(Ws + (p) + b0 + ns * 1024);                \
            bw[ns][1] = *(const bf16x8*)(Ws + (p) + b0 + ns * 1024 + 512);          \
        }                                                                           \
        __builtin_amdgcn_s_setprio(1);                                              \
        _Pragma("unroll") for (int ms = 0; ms < 2; ++ms)                            \
            _Pragma("unroll") for (int ns = 0; ns < 2; ++ns) {                      \
                aS[ms][ns] = M32(af[ms][0], bu[ns][0], aS[ms][ns]);                 \
                aG[ms][ns] = M32(af[ms][0], bw[ns][0], aG[ms][ns]);                 \
            }                                                                       \
        _Pragma("unroll") for (int ms = 0; ms < 2; ++ms)                            \
            _Pragma("unroll") for (int ns = 0; ns < 2; ++ns) {                      \
                aS[ms][ns] = M32(af[ms][1], bu[ns][1], aS[ms][ns]);                 \
                aG[ms][ns] = M32(af[ms][1], bw[ns][1], aG[ms][ns]);                 \
            }                                                                       \
        __builtin_amdgcn_s_setprio(0);                                              \
    }

#define WAITV(n) asm volatile("s_waitcnt vmcnt(" #n ")" ::: "memory"); \
                 __builtin_amdgcn_sched_barrier(0)
#define WAITL    asm volatile("s_waitcnt lgkmcnt(0)" ::: "memory")
#define BAR      __builtin_amdgcn_s_barrier()

// one K-tile, SINGLE barrier: WAITL (my reads of buf P-1 done) + WAITV(6) (my GLLs
// for tile P done; tiles P+1 in flight) BEFORE the barrier; stage buf P-1 with tile
// P+2 and compute tile P AFTER it.
#define TILE1(P)                                                        \
    WAITL; WAITV(6); BAR;                                               \
    STAGE(((P) + 2) % 3)                                                \
    COMPUTE((P) * 4096)

    // prologue: tiles 0,1 in flight (12 outstanding GLLs per thread)
    STAGE(0)
    STAGE(1)

    // iters 0..21 full (stage tiles 2..23); tail 22,23 without staging
    for (int g = 0; g < 7; ++g) {
        TILE1(0)
        TILE1(1)
        TILE1(2)
    }
    TILE1(0)                                  // iter 21 (stages tile 23 -> buf 2)
    WAITL; WAITV(6); BAR; COMPUTE(1 * 4096)   // iter 22 (completes tile 22)
    WAITL; WAITV(0); BAR; COMPUTE(2 * 4096)   // iter 23
#undef TILE1
#undef COMPUTE
#undef STAGE

    // epilogue (32x32 C/D: col = lane&31 = y; rows = permutation of the 32 l-values
    // across (reg, lane>>5) -- reduction over l is permutation-invariant). R16-verified.
    #pragma unroll
    for (int ns = 0; ns < 2; ++ns) {
        const int y = n0 + wn + ns * 32 + l31;
        float rs = 0.f, ys = 0.f;
        #pragma unroll
        for (int ms = 0; ms < 2; ++ms) {
            #pragma unroll
            for (int rr = 0; rr < 16; ++rr) {
                float e = __expf(aS[ms][ns][rr]);
                rs += e;
                ys += e * aG[ms][ns][rr];
            }
        }
        rs += __shfl_xor(rs, 32, 64);  ys += __shfl_xor(ys, 32, 64);
        if (lh == 0) {
            atomicAdd(&rowsum[y], rs);
            atomicAdd(&ynum[y], ys);
        }
    }

    // ---- last-block CE (fused; saves the ce_loss dispatch) ----
    __threadfence();                         // my rowsum/ynum atomics before counter add
    if (t == 0) lastB = (atomicAdd((int*)out0, 1) == NBLK - 1) ? 1 : 0;
    __syncthreads();
    if (lastB) {
        __threadfence();
        float totl = 0.f;
        for (int bb = 0; bb < BB; ++bb) {
            const float* yn = ynum0 + bb * YY;
            const float* rsm = rowsum0 + bb * YY;
            float* row = yv + bb * YY;
            const int tg = tgt[bb];
            float v[8];
            float mx = -3.0e38f, tv = 0.f;
            #pragma unroll
            for (int i = 0; i < 8; ++i) {
                const int idx = t + 256 * i;
                // agent-scope loads: see other XCDs' device-scope atomic results
                float a = __hip_atomic_load(&yn[idx], __ATOMIC_RELAXED, __HIP_MEMORY_SCOPE_AGENT);
                float c = __hip_atomic_load(&rsm[idx], __ATOMIC_RELAXED, __HIP_MEMORY_SCOPE_AGENT);
                v[i] = a / c + fb[idx];
                row[idx] = v[i];             // write final y
                mx = fmaxf(mx, v[i]);
                if (idx == tg) tv = v[i];
            }
            #pragma unroll
            for (int o = 32; o; o >>= 1) mx = fmaxf(mx, __shfl_xor(mx, o, 64));
            if (lane == 0) smx[w] = mx;
            __syncthreads();
            mx = fmaxf(fmaxf(smx[0], smx[1]), fmaxf(smx[2], smx[3]));
            float s = 0.f;
            #pragma unroll
            for (int i = 0; i < 8; ++i) s += __expf(v[i] - mx);
            #pragma unroll
            for (int o = 32; o; o >>= 1) { s += __shfl_xor(s, o, 64); tv += __shfl_xor(tv, o, 64); }
            if (lane == 0) { ssum[w] = s; stv2[w] = tv; }
            __syncthreads();
            if (t == 0)
                totl += mx + logf(ssum[0] + ssum[1] + ssum[2] + ssum[3])
                           - (stv2[0] + stv2[1] + stv2[2] + stv2[3]);
            __syncthreads();                 // protect smx/ssum reuse next batch
        }
        if (t == 0) out0[0] = totl * 0.125f; // overwrites the block counter
    }
}

extern "C" void kernel_launch(void* const* d_in, const int* in_sizes, int n_in,
                              void* d_out, int out_size, void* d_ws, size_t ws_size,
                              hipStream_t stream) {
    const float* x   = (const float*)d_in[0];   // (B,L,D)
    const float* Uw  = (const float*)d_in[1];   // (Y,D)
    const float* fw  = (const float*)d_in[2];   // (Y,D)
    const float* fb  = (const float*)d_in[3];   // (Y,)
    const int*   tgt = (const int*)d_in[4];     // (B,)
    float* out = (float*)d_out;                 // [loss, y(B*Y)]

    char* ws = (char*)d_ws;
    u16*  x16  = (u16*)(ws);                          // B*L*D bf16 = 50,331,648 B (tiled)
    u16*  U16  = (u16*)(ws + 50331648);               // Y*D bf16   =  3,145,728 B (tiled)
    u16*  fw16 = (u16*)(ws + 53477376);               // Y*D bf16   =  3,145,728 B (tiled)
    float* rowsum = (float*)(ws + 56623104);          // B*Y fp32   =     65,536 B
    float* ynum   = (float*)(ws + 56688640);          // B*Y fp32   =     65,536 B

    // prologue: tiled casts + zero rowsum/ynum + zero block counter (= out[0])
    prep_k<<<27648, 256, 0, stream>>>(x, Uw, fw, x16, U16, fw16, rowsum, out);

    // Fused S/G GEMM + exp + reductions + last-block CE: 4096 blocks
    fused_k<<<NBLK, 256, 0, stream>>>(x16, U16, fw16, rowsum, ynum,
                                      fb, tgt, out, out + 1);
}